// Round 1
// baseline (331.262 us; speedup 1.0000x reference)
//
#include <hip/hip_runtime.h>
#include <hip/hip_bf16.h>

typedef float f32x4 __attribute__((ext_vector_type(4)));
typedef __bf16 bf16x8 __attribute__((ext_vector_type(8)));
typedef unsigned short ushort4v __attribute__((ext_vector_type(4)));

#define MFMA16(a, b, c) __builtin_amdgcn_mfma_f32_16x16x32_bf16((a), (b), (c), 0, 0, 0)

__device__ __forceinline__ unsigned short f2bf(float f) {
    union { float f; unsigned int u; } v; v.f = f;
    unsigned int r = (v.u + 0x7fffu + ((v.u >> 16) & 1u)) >> 16;  // RNE
    return (unsigned short)r;
}

// ---------------------------------------------------------------------------
// Projection GEMM: out[m][c] (or transposed out[c][m]) = bf16((E[m][:] . W[:][c] + bias[c]) * scale)
// M = 16384 rows (4 batches x 4096), K = 512, NC = 64 or 512.
// Tile: BM=128, BN=64, BK=32. 256 threads = 4 waves (2x2), each wave 64x32.
// ---------------------------------------------------------------------------
template <int NC, bool TRV>
__global__ __launch_bounds__(256) void proj_kernel(const float* __restrict__ E,
                                                   const float* __restrict__ W,
                                                   const float* __restrict__ bias,
                                                   unsigned short* __restrict__ out,
                                                   float scale)
{
    __shared__ __align__(16) unsigned short Al[128][40];  // [row][k], +8 pad
    __shared__ __align__(16) unsigned short Bl[64][40];   // [col][k], +8 pad

    const int tid = threadIdx.x;
    const int w = tid >> 6, l = tid & 63, g = l >> 4, li = l & 15;
    const int wm = w >> 1, wn = w & 1;
    const int row0 = blockIdx.x * 128;
    const int c0 = blockIdx.y * 64;

    f32x4 acc[4][2];
#pragma unroll
    for (int mb = 0; mb < 4; ++mb)
#pragma unroll
        for (int nb = 0; nb < 2; ++nb) acc[mb][nb] = (f32x4)0.0f;

    const int arow = tid >> 3;       // 0..31
    const int ak = (tid & 7) * 4;    // 0..28
    const int bk = tid >> 4;         // 0..15
    const int bc = (tid & 15) * 4;   // 0..60

    for (int kt = 0; kt < 16; ++kt) {
        const int k0 = kt * 32;
        // stage A: E fp32 -> bf16 LDS, row-major [128][32]
#pragma unroll
        for (int i = 0; i < 4; ++i) {
            const int r = arow + 32 * i;
            f32x4 v = *(const f32x4*)&E[(size_t)(row0 + r) * 512 + k0 + ak];
            ushort4v u;
#pragma unroll
            for (int j = 0; j < 4; ++j) u[j] = f2bf(v[j]);
            *(ushort4v*)&Al[r][ak] = u;
        }
        // stage B transposed: Bl[c][k] = W[k0+k][c0+c]
#pragma unroll
        for (int i = 0; i < 2; ++i) {
            const int kk = bk + 16 * i;
            f32x4 v = *(const f32x4*)&W[(size_t)(k0 + kk) * NC + c0 + bc];
#pragma unroll
            for (int j = 0; j < 4; ++j) Bl[bc + j][kk] = f2bf(v[j]);
        }
        __syncthreads();

        bf16x8 af[4], bw[2];
#pragma unroll
        for (int mb = 0; mb < 4; ++mb) af[mb] = *(const bf16x8*)&Al[wm * 64 + mb * 16 + li][8 * g];
#pragma unroll
        for (int nb = 0; nb < 2; ++nb) bw[nb] = *(const bf16x8*)&Bl[wn * 32 + nb * 16 + li][8 * g];
#pragma unroll
        for (int mb = 0; mb < 4; ++mb)
#pragma unroll
            for (int nb = 0; nb < 2; ++nb) acc[mb][nb] = MFMA16(af[mb], bw[nb], acc[mb][nb]);
        __syncthreads();
    }

    // epilogue
    float bv[2];
#pragma unroll
    for (int nb = 0; nb < 2; ++nb) bv[nb] = bias[c0 + wn * 32 + nb * 16 + li];
#pragma unroll
    for (int mb = 0; mb < 4; ++mb) {
#pragma unroll
        for (int nb = 0; nb < 2; ++nb) {
            const int col = c0 + wn * 32 + nb * 16 + li;
            const int grow0 = row0 + wm * 64 + mb * 16 + 4 * g;  // +r, rows within one batch tile
            if (TRV) {
                ushort4v u;
#pragma unroll
                for (int r = 0; r < 4; ++r) u[r] = f2bf((acc[mb][nb][r] + bv[nb]) * scale);
                const int bb = grow0 >> 12, n = grow0 & 4095;
                *(ushort4v*)(out + ((size_t)bb * 512 + col) * 4096 + n) = u;
            } else {
#pragma unroll
                for (int r = 0; r < 4; ++r)
                    out[(size_t)(grow0 + r) * NC + col] = f2bf((acc[mb][nb][r] + bv[nb]) * scale);
            }
        }
    }
}

// ---------------------------------------------------------------------------
// Causal flash attention.
// Grid: 512 blocks = 64 q-tiles x 4 batches x 2 col-halves, descending q-tile.
// Block: 512 threads = 8 waves. Q-tile 64 rows, col chunk 256 (of 512 V dims).
// Per kv-tile (64): waves 0-3 compute S(16x64) + online softmax + P->LDS;
// barrier; all 8 waves do PV (each 32 V-cols) with V frags from global Vt.
// Q pre-scaled by 1/8 at projection time.
// ---------------------------------------------------------------------------
__global__ __launch_bounds__(512) void attn_kernel(const unsigned short* __restrict__ Qb,
                                                   const unsigned short* __restrict__ Kb,
                                                   const unsigned short* __restrict__ Vt,
                                                   float* __restrict__ out)
{
    __shared__ __align__(16) unsigned short Pl[64][72];  // [q][kv], +8 pad
    __shared__ __align__(16) float scl_l[64];
    __shared__ __align__(16) float lsum_l[64];

    const int tid = threadIdx.x;
    const int w = tid >> 6, l = tid & 63, g = l >> 4, li = l & 15;
    const int bid = blockIdx.x;
    const int t = bid >> 3;
    const int b = (bid >> 1) & 3;
    const int ch = bid & 1;
    const int qt = 63 - t;  // big tiles dispatched first
    const int q0 = qt * 64;

    bf16x8 QA[2];
    float m_r[4], l_r[4];
    if (w < 4) {
        const unsigned short* qptr = Qb + ((size_t)(b * 4096 + q0 + 16 * w + li)) * 64 + 8 * g;
        QA[0] = *(const bf16x8*)qptr;
        QA[1] = *(const bf16x8*)(qptr + 32);
#pragma unroll
        for (int r = 0; r < 4; ++r) { m_r[r] = -INFINITY; l_r[r] = 0.0f; }
    }

    f32x4 Of[4][2];
#pragma unroll
    for (int qb = 0; qb < 4; ++qb) { Of[qb][0] = (f32x4)0.0f; Of[qb][1] = (f32x4)0.0f; }

    const unsigned short* kbase = Kb + ((size_t)(b * 4096 + li)) * 64 + 8 * g;
    const int cglob = ch * 256 + w * 32 + li;  // this thread's V-col (per cf add 16)
    const unsigned short* vbase = Vt + ((size_t)(b * 512)) * 4096 + 8 * g;

    for (int kt = 0; kt <= qt; ++kt) {
        const int kv0 = kt * 64;
        if (w < 4) {
            // S = Q K^T (pre-scaled): 16 q rows x 64 kv
            f32x4 S[4];
#pragma unroll
            for (int cb = 0; cb < 4; ++cb) {
                S[cb] = (f32x4)0.0f;
#pragma unroll
                for (int ks = 0; ks < 2; ++ks) {
                    bf16x8 KB = *(const bf16x8*)(kbase + (size_t)(kv0 + cb * 16) * 64 + ks * 32);
                    S[cb] = MFMA16(QA[ks], KB, S[cb]);
                }
            }
            if (kt == qt) {  // diagonal tile: causal mask
#pragma unroll
                for (int cb = 0; cb < 4; ++cb)
#pragma unroll
                    for (int r = 0; r < 4; ++r)
                        if (cb * 16 + li > 16 * w + 4 * g + r) S[cb][r] = -1e30f;
            }
            // online softmax, rows owned by 16-lane groups (4 rows/lane in regs)
            float pm[4], rs[4], sc[4];
#pragma unroll
            for (int r = 0; r < 4; ++r)
                pm[r] = fmaxf(fmaxf(S[0][r], S[1][r]), fmaxf(S[2][r], S[3][r]));
#pragma unroll
            for (int d = 1; d < 16; d <<= 1)
#pragma unroll
                for (int r = 0; r < 4; ++r) pm[r] = fmaxf(pm[r], __shfl_xor(pm[r], d));
#pragma unroll
            for (int r = 0; r < 4; ++r) {
                const float mn = fmaxf(m_r[r], pm[r]);
                sc[r] = __expf(m_r[r] - mn);
                m_r[r] = mn;
                rs[r] = 0.0f;
            }
#pragma unroll
            for (int cb = 0; cb < 4; ++cb)
#pragma unroll
                for (int r = 0; r < 4; ++r) {
                    const float p = __expf(S[cb][r] - m_r[r]);
                    S[cb][r] = p;
                    rs[r] += p;
                }
#pragma unroll
            for (int d = 1; d < 16; d <<= 1)
#pragma unroll
                for (int r = 0; r < 4; ++r) rs[r] += __shfl_xor(rs[r], d);
#pragma unroll
            for (int r = 0; r < 4; ++r) l_r[r] = l_r[r] * sc[r] + rs[r];
            // P -> LDS (bf16), rescale factors -> LDS
#pragma unroll
            for (int cb = 0; cb < 4; ++cb)
#pragma unroll
                for (int r = 0; r < 4; ++r)
                    Pl[16 * w + 4 * g + r][cb * 16 + li] = f2bf(S[cb][r]);
            if (li == 0) {
#pragma unroll
                for (int r = 0; r < 4; ++r) scl_l[16 * w + 4 * g + r] = sc[r];
            }
        }
        __syncthreads();

        // Phase B: PV for this wave's 32 V-cols, all 64 q rows
        bf16x8 VB[2][2];
#pragma unroll
        for (int cf = 0; cf < 2; ++cf)
#pragma unroll
            for (int ks = 0; ks < 2; ++ks)
                VB[cf][ks] = *(const bf16x8*)(vbase + (size_t)(cglob + cf * 16) * 4096 + kv0 + ks * 32);
#pragma unroll
        for (int qb = 0; qb < 4; ++qb) {
            f32x4 scv = *(const f32x4*)&scl_l[qb * 16 + 4 * g];
            bf16x8 PA0 = *(const bf16x8*)&Pl[qb * 16 + li][8 * g];
            bf16x8 PA1 = *(const bf16x8*)&Pl[qb * 16 + li][32 + 8 * g];
#pragma unroll
            for (int cf = 0; cf < 2; ++cf) {
                f32x4 o = Of[qb][cf];
#pragma unroll
                for (int r = 0; r < 4; ++r) o[r] *= scv[r];
                o = MFMA16(PA0, VB[cf][0], o);
                o = MFMA16(PA1, VB[cf][1], o);
                Of[qb][cf] = o;
            }
        }
        __syncthreads();
    }

    // normalize by row sums and store fp32
    if (w < 4 && li == 0) {
#pragma unroll
        for (int r = 0; r < 4; ++r) lsum_l[16 * w + 4 * g + r] = l_r[r];
    }
    __syncthreads();

    float* obase = out + (size_t)(b * 4096 + q0 + 4 * g) * 512 + cglob;
#pragma unroll
    for (int qb = 0; qb < 4; ++qb) {
        f32x4 lv = *(const f32x4*)&lsum_l[qb * 16 + 4 * g];
#pragma unroll
        for (int cf = 0; cf < 2; ++cf)
#pragma unroll
            for (int r = 0; r < 4; ++r)
                obase[(size_t)(qb * 16 + r) * 512 + cf * 16] = Of[qb][cf][r] / lv[r];
    }
}

// ---------------------------------------------------------------------------
extern "C" void kernel_launch(void* const* d_in, const int* in_sizes, int n_in,
                              void* d_out, int out_size, void* d_ws, size_t ws_size,
                              hipStream_t stream)
{
    (void)in_sizes; (void)n_in; (void)out_size; (void)ws_size;
    const float* E  = (const float*)d_in[0];
    // d_in[1] = mask (tril causal) -- handled analytically
    const float* wq = (const float*)d_in[2];
    const float* bq = (const float*)d_in[3];
    const float* wk = (const float*)d_in[4];
    const float* bk = (const float*)d_in[5];
    const float* wv = (const float*)d_in[6];
    const float* bv = (const float*)d_in[7];

    unsigned short* Qb = (unsigned short*)d_ws;                 // [4][4096][64] bf16 (x0.125)
    unsigned short* Kb = Qb + (size_t)4 * 4096 * 64;            // [4][4096][64] bf16
    unsigned short* Vt = Kb + (size_t)4 * 4096 * 64;            // [4][512][4096] bf16 (transposed)
    float* out = (float*)d_out;

    proj_kernel<64, false><<<dim3(128, 1), 256, 0, stream>>>(E, wq, bq, Qb, 0.125f);
    proj_kernel<64, false><<<dim3(128, 1), 256, 0, stream>>>(E, wk, bk, Kb, 1.0f);
    proj_kernel<512, true><<<dim3(128, 8), 256, 0, stream>>>(E, wv, bv, Vt, 1.0f);
    attn_kernel<<<dim3(512), 512, 0, stream>>>(Qb, Kb, Vt, out);
}

// Round 2
// 275.939 us; speedup vs baseline: 1.2005x; 1.2005x over previous
//
#include <hip/hip_runtime.h>
#include <hip/hip_bf16.h>

typedef float f32x4 __attribute__((ext_vector_type(4)));
typedef __bf16 bf16x8 __attribute__((ext_vector_type(8)));
typedef unsigned short ushort4v __attribute__((ext_vector_type(4)));
typedef unsigned short ushort8v __attribute__((ext_vector_type(8)));

#define MFMA16(a, b, c) __builtin_amdgcn_mfma_f32_16x16x32_bf16((a), (b), (c), 0, 0, 0)

__device__ __forceinline__ unsigned short f2bf(float f) {
    union { float f; unsigned int u; } v; v.f = f;
    unsigned int r = (v.u + 0x7fffu + ((v.u >> 16) & 1u)) >> 16;  // RNE
    return (unsigned short)r;
}

// ---------------------------------------------------------------------------
// E -> bf16 conversion (one pass). 8.4M elements, 8 per thread.
// ---------------------------------------------------------------------------
__global__ __launch_bounds__(256) void conv_kernel(const float* __restrict__ E,
                                                   unsigned short* __restrict__ Eb)
{
    const size_t i = ((size_t)blockIdx.x * 256 + threadIdx.x) * 8;
    f32x4 a = *(const f32x4*)&E[i];
    f32x4 b = *(const f32x4*)&E[i + 4];
    ushort8v u;
#pragma unroll
    for (int j = 0; j < 4; ++j) { u[j] = f2bf(a[j]); u[4 + j] = f2bf(b[j]); }
    *(ushort8v*)&Eb[i] = u;
}

// ---------------------------------------------------------------------------
// Projection GEMM: out = bf16((A . W + bias) * scale), A = E (bf16 or fp32).
// M=16384, K=512. Tile BM=128 x BN(64|128), BK=32. 256 threads, 4 waves (2x2),
// wave tile 64 x BN/2.
// ---------------------------------------------------------------------------
template <int NC, int BN, bool TRV, bool BF16A>
__global__ __launch_bounds__(256) void proj_kernel(const void* __restrict__ Ein,
                                                   const float* __restrict__ W,
                                                   const float* __restrict__ bias,
                                                   unsigned short* __restrict__ out,
                                                   float scale)
{
    constexpr int NB = BN / 32;        // n-frags per wave
    constexpr int CPW = BN / 4;        // f32x4 cols per k-row (B staging)
    constexpr int KROWS = 256 / CPW;   // k-rows per staging pass
    constexpr int BI = 32 / KROWS;     // B staging passes

    __shared__ __align__(16) unsigned short Al[128][40];
    __shared__ __align__(16) unsigned short Bl[BN][40];

    const int tid = threadIdx.x;
    const int w = tid >> 6, l = tid & 63, g = l >> 4, li = l & 15;
    const int wm = w >> 1, wn = w & 1;
    const int row0 = blockIdx.x * 128;
    const int c0 = blockIdx.y * BN;

    f32x4 acc[4][NB];
#pragma unroll
    for (int mb = 0; mb < 4; ++mb)
#pragma unroll
        for (int nb = 0; nb < NB; ++nb) acc[mb][nb] = (f32x4)0.0f;

    for (int kt = 0; kt < 16; ++kt) {
        const int k0 = kt * 32;
        if (BF16A) {
            const unsigned short* Eb = (const unsigned short*)Ein;
#pragma unroll
            for (int i = 0; i < 2; ++i) {
                const int r = (tid >> 2) + 64 * i;
                *(ushort8v*)&Al[r][(tid & 3) * 8] =
                    *(const ushort8v*)&Eb[(size_t)(row0 + r) * 512 + k0 + (tid & 3) * 8];
            }
        } else {
            const float* E = (const float*)Ein;
#pragma unroll
            for (int i = 0; i < 4; ++i) {
                const int r = (tid >> 3) + 32 * i;
                f32x4 v = *(const f32x4*)&E[(size_t)(row0 + r) * 512 + k0 + (tid & 7) * 4];
                ushort4v u;
#pragma unroll
                for (int j = 0; j < 4; ++j) u[j] = f2bf(v[j]);
                *(ushort4v*)&Al[r][(tid & 7) * 4] = u;
            }
        }
        // stage B transposed: Bl[c][k] = W[k0+k][c0+c]
#pragma unroll
        for (int i = 0; i < BI; ++i) {
            const int kk = (tid / CPW) + KROWS * i;
            const int cc = (tid % CPW) * 4;
            f32x4 v = *(const f32x4*)&W[(size_t)(k0 + kk) * NC + c0 + cc];
#pragma unroll
            for (int j = 0; j < 4; ++j) Bl[cc + j][kk] = f2bf(v[j]);
        }
        __syncthreads();

        bf16x8 af[4], bw[NB];
#pragma unroll
        for (int mb = 0; mb < 4; ++mb) af[mb] = *(const bf16x8*)&Al[wm * 64 + mb * 16 + li][8 * g];
#pragma unroll
        for (int nb = 0; nb < NB; ++nb)
            bw[nb] = *(const bf16x8*)&Bl[wn * (BN / 2) + nb * 16 + li][8 * g];
#pragma unroll
        for (int mb = 0; mb < 4; ++mb)
#pragma unroll
            for (int nb = 0; nb < NB; ++nb) acc[mb][nb] = MFMA16(af[mb], bw[nb], acc[mb][nb]);
        __syncthreads();
    }

    float bv[NB];
#pragma unroll
    for (int nb = 0; nb < NB; ++nb) bv[nb] = bias[c0 + wn * (BN / 2) + nb * 16 + li];
#pragma unroll
    for (int mb = 0; mb < 4; ++mb) {
#pragma unroll
        for (int nb = 0; nb < NB; ++nb) {
            const int col = c0 + wn * (BN / 2) + nb * 16 + li;
            const int grow0 = row0 + wm * 64 + mb * 16 + 4 * g;
            if (TRV) {
                ushort4v u;
#pragma unroll
                for (int r = 0; r < 4; ++r) u[r] = f2bf((acc[mb][nb][r] + bv[nb]) * scale);
                const int bb = grow0 >> 12, n = grow0 & 4095;
                *(ushort4v*)(out + ((size_t)bb * 512 + col) * 4096 + n) = u;
            } else {
#pragma unroll
                for (int r = 0; r < 4; ++r)
                    out[(size_t)(grow0 + r) * NC + col] = f2bf((acc[mb][nb][r] + bv[nb]) * scale);
            }
        }
    }
}

// ---------------------------------------------------------------------------
// Causal flash attention, v2: register prefetch of K/V one kv-tile ahead +
// balanced CU pairing (co-resident block pair sums to 63 iters).
// Grid 512 = 64 q-tiles x 4 b x 2 col-halves. 512 threads = 8 waves.
// Per kv-tile(64): issue K(next)/V(next) loads; waves 0-3 S+softmax+P->LDS;
// barrier; all waves PV (32 V-cols each) with prefetched V; barrier.
// ---------------------------------------------------------------------------
__global__ __launch_bounds__(512) void attn_kernel(const unsigned short* __restrict__ Qb,
                                                   const unsigned short* __restrict__ Kb,
                                                   const unsigned short* __restrict__ Vt,
                                                   float* __restrict__ out)
{
    __shared__ __align__(16) unsigned short Pl[64][72];
    __shared__ __align__(16) float scl_l[64];
    __shared__ __align__(16) float lsum_l[64];

    const int tid = threadIdx.x;
    const int w = tid >> 6, l = tid & 63, g = l >> 4, li = l & 15;
    const int bid = blockIdx.x;
    const int t = bid >> 3;
    const int b = (bid >> 1) & 3;
    const int ch = bid & 1;
    // balanced pairing: blocks c and c+256 land on the same CU; their qt sum to 63
    const int qt = (t < 32) ? (63 - t) : (t - 32);
    const int q0 = qt * 64;

    bf16x8 QA[2];
    float m_r[4], l_r[4];
    const unsigned short* kbase = Kb + ((size_t)(b * 4096 + li)) * 64 + 8 * g;
    if (w < 4) {
        const unsigned short* qptr = Qb + ((size_t)(b * 4096 + q0 + 16 * w + li)) * 64 + 8 * g;
        QA[0] = *(const bf16x8*)qptr;
        QA[1] = *(const bf16x8*)(qptr + 32);
#pragma unroll
        for (int r = 0; r < 4; ++r) { m_r[r] = -INFINITY; l_r[r] = 0.0f; }
    }

    f32x4 Of[4][2];
#pragma unroll
    for (int qb = 0; qb < 4; ++qb) { Of[qb][0] = (f32x4)0.0f; Of[qb][1] = (f32x4)0.0f; }

    const int cglob = ch * 256 + w * 32 + li;
    const unsigned short* vbase = Vt + ((size_t)(b * 512)) * 4096 + 8 * g;

    // prologue: load tile 0 into current regs
    bf16x8 KB[4][2], KBn[4][2], VB[2][2], VBn[2][2];
    if (w < 4) {
#pragma unroll
        for (int cb = 0; cb < 4; ++cb)
#pragma unroll
            for (int ks = 0; ks < 2; ++ks)
                KB[cb][ks] = *(const bf16x8*)(kbase + (size_t)(cb * 16) * 64 + ks * 32);
    }
#pragma unroll
    for (int cf = 0; cf < 2; ++cf)
#pragma unroll
        for (int ks = 0; ks < 2; ++ks)
            VB[cf][ks] = *(const bf16x8*)(vbase + (size_t)(cglob + cf * 16) * 4096 + ks * 32);

    for (int kt = 0; kt <= qt; ++kt) {
        const int kv0 = kt * 64;
        const int kvn = (kt < qt ? kt + 1 : kt) * 64;

        // issue next-tile prefetch first (consumed next iteration)
        if (w < 4) {
#pragma unroll
            for (int cb = 0; cb < 4; ++cb)
#pragma unroll
                for (int ks = 0; ks < 2; ++ks)
                    KBn[cb][ks] = *(const bf16x8*)(kbase + (size_t)(kvn + cb * 16) * 64 + ks * 32);
        }
#pragma unroll
        for (int cf = 0; cf < 2; ++cf)
#pragma unroll
            for (int ks = 0; ks < 2; ++ks)
                VBn[cf][ks] = *(const bf16x8*)(vbase + (size_t)(cglob + cf * 16) * 4096 + kvn + ks * 32);

        if (w < 4) {
            f32x4 S[4];
#pragma unroll
            for (int cb = 0; cb < 4; ++cb) {
                S[cb] = (f32x4)0.0f;
#pragma unroll
                for (int ks = 0; ks < 2; ++ks) S[cb] = MFMA16(QA[ks], KB[cb][ks], S[cb]);
            }
            if (kt == qt) {
#pragma unroll
                for (int cb = 0; cb < 4; ++cb)
#pragma unroll
                    for (int r = 0; r < 4; ++r)
                        if (cb * 16 + li > 16 * w + 4 * g + r) S[cb][r] = -1e30f;
            }
            float pm[4], rs[4], sc[4];
#pragma unroll
            for (int r = 0; r < 4; ++r)
                pm[r] = fmaxf(fmaxf(S[0][r], S[1][r]), fmaxf(S[2][r], S[3][r]));
#pragma unroll
            for (int d = 1; d < 16; d <<= 1)
#pragma unroll
                for (int r = 0; r < 4; ++r) pm[r] = fmaxf(pm[r], __shfl_xor(pm[r], d));
#pragma unroll
            for (int r = 0; r < 4; ++r) {
                const float mn = fmaxf(m_r[r], pm[r]);
                sc[r] = __expf(m_r[r] - mn);
                m_r[r] = mn;
                rs[r] = 0.0f;
            }
#pragma unroll
            for (int cb = 0; cb < 4; ++cb)
#pragma unroll
                for (int r = 0; r < 4; ++r) {
                    const float p = __expf(S[cb][r] - m_r[r]);
                    S[cb][r] = p;
                    rs[r] += p;
                }
#pragma unroll
            for (int d = 1; d < 16; d <<= 1)
#pragma unroll
                for (int r = 0; r < 4; ++r) rs[r] += __shfl_xor(rs[r], d);
#pragma unroll
            for (int r = 0; r < 4; ++r) l_r[r] = l_r[r] * sc[r] + rs[r];
#pragma unroll
            for (int cb = 0; cb < 4; ++cb)
#pragma unroll
                for (int r = 0; r < 4; ++r)
                    Pl[16 * w + 4 * g + r][cb * 16 + li] = f2bf(S[cb][r]);
            if (li == 0) {
#pragma unroll
                for (int r = 0; r < 4; ++r) scl_l[16 * w + 4 * g + r] = sc[r];
            }
        }
        __syncthreads();

        // Phase B: PV with prefetched V
#pragma unroll
        for (int qb = 0; qb < 4; ++qb) {
            f32x4 scv = *(const f32x4*)&scl_l[qb * 16 + 4 * g];
            bf16x8 PA0 = *(const bf16x8*)&Pl[qb * 16 + li][8 * g];
            bf16x8 PA1 = *(const bf16x8*)&Pl[qb * 16 + li][32 + 8 * g];
#pragma unroll
            for (int cf = 0; cf < 2; ++cf) {
                f32x4 o = Of[qb][cf];
#pragma unroll
                for (int r = 0; r < 4; ++r) o[r] *= scv[r];
                o = MFMA16(PA0, VB[cf][0], o);
                o = MFMA16(PA1, VB[cf][1], o);
                Of[qb][cf] = o;
            }
        }
        __syncthreads();

        // rotate prefetch regs
        if (w < 4) {
#pragma unroll
            for (int cb = 0; cb < 4; ++cb)
#pragma unroll
                for (int ks = 0; ks < 2; ++ks) KB[cb][ks] = KBn[cb][ks];
        }
#pragma unroll
        for (int cf = 0; cf < 2; ++cf)
#pragma unroll
            for (int ks = 0; ks < 2; ++ks) VB[cf][ks] = VBn[cf][ks];
    }

    if (w < 4 && li == 0) {
#pragma unroll
        for (int r = 0; r < 4; ++r) lsum_l[16 * w + 4 * g + r] = l_r[r];
    }
    __syncthreads();

    float* obase = out + (size_t)(b * 4096 + q0 + 4 * g) * 512 + cglob;
#pragma unroll
    for (int qb = 0; qb < 4; ++qb) {
        f32x4 lv = *(const f32x4*)&lsum_l[qb * 16 + 4 * g];
#pragma unroll
        for (int cf = 0; cf < 2; ++cf)
#pragma unroll
            for (int r = 0; r < 4; ++r)
                obase[(size_t)(qb * 16 + r) * 512 + cf * 16] = Of[qb][cf][r] / lv[r];
    }
}

// ---------------------------------------------------------------------------
extern "C" void kernel_launch(void* const* d_in, const int* in_sizes, int n_in,
                              void* d_out, int out_size, void* d_ws, size_t ws_size,
                              hipStream_t stream)
{
    (void)in_sizes; (void)n_in; (void)out_size;
    const float* E  = (const float*)d_in[0];
    const float* wq = (const float*)d_in[2];
    const float* bq = (const float*)d_in[3];
    const float* wk = (const float*)d_in[4];
    const float* bk = (const float*)d_in[5];
    const float* wv = (const float*)d_in[6];
    const float* bv = (const float*)d_in[7];

    const size_t qk_elems = (size_t)4 * 4096 * 64;
    const size_t vt_elems = (size_t)4 * 512 * 4096;
    const size_t eb_elems = (size_t)4 * 4096 * 512;

    unsigned short* Qb = (unsigned short*)d_ws;
    unsigned short* Kb = Qb + qk_elems;
    unsigned short* Vt = Kb + qk_elems;
    unsigned short* Eb = Vt + vt_elems;
    float* out = (float*)d_out;

    const size_t need_bf16 = (2 * qk_elems + vt_elems + eb_elems) * sizeof(unsigned short);
    if (ws_size >= need_bf16) {
        conv_kernel<<<dim3(4096), 256, 0, stream>>>(E, Eb);
        proj_kernel<64, 64, false, true><<<dim3(128, 1), 256, 0, stream>>>(Eb, wq, bq, Qb, 0.125f);
        proj_kernel<64, 64, false, true><<<dim3(128, 1), 256, 0, stream>>>(Eb, wk, bk, Kb, 1.0f);
        proj_kernel<512, 128, true, true><<<dim3(128, 4), 256, 0, stream>>>(Eb, wv, bv, Vt, 1.0f);
    } else {
        proj_kernel<64, 64, false, false><<<dim3(128, 1), 256, 0, stream>>>(E, wq, bq, Qb, 0.125f);
        proj_kernel<64, 64, false, false><<<dim3(128, 1), 256, 0, stream>>>(E, wk, bk, Kb, 1.0f);
        proj_kernel<512, 128, true, false><<<dim3(128, 4), 256, 0, stream>>>(E, wv, bv, Vt, 1.0f);
    }
    attn_kernel<<<dim3(512), 512, 0, stream>>>(Qb, Kb, Vt, out);
}

// Round 3
// 273.812 us; speedup vs baseline: 1.2098x; 1.0078x over previous
//
#include <hip/hip_runtime.h>
#include <hip/hip_bf16.h>

typedef float f32x4 __attribute__((ext_vector_type(4)));
typedef __bf16 bf16x8 __attribute__((ext_vector_type(8)));
typedef unsigned short ushort4v __attribute__((ext_vector_type(4)));
typedef unsigned short ushort8v __attribute__((ext_vector_type(8)));

#define MFMA16(a, b, c) __builtin_amdgcn_mfma_f32_16x16x32_bf16((a), (b), (c), 0, 0, 0)

__device__ __forceinline__ unsigned short f2bf(float f) {
    union { float f; unsigned int u; } v; v.f = f;
    unsigned int r = (v.u + 0x7fffu + ((v.u >> 16) & 1u)) >> 16;  // RNE
    return (unsigned short)r;
}
__device__ __forceinline__ int imin(int a, int b) { return a < b ? a : b; }

// ---------------------------------------------------------------------------
// E -> bf16 conversion (one pass).
// ---------------------------------------------------------------------------
__global__ __launch_bounds__(256) void conv_kernel(const float* __restrict__ E,
                                                   unsigned short* __restrict__ Eb)
{
    const size_t i = ((size_t)blockIdx.x * 256 + threadIdx.x) * 8;
    f32x4 a = *(const f32x4*)&E[i];
    f32x4 b = *(const f32x4*)&E[i + 4];
    ushort8v u;
#pragma unroll
    for (int j = 0; j < 4; ++j) { u[j] = f2bf(a[j]); u[4 + j] = f2bf(b[j]); }
    *(ushort8v*)&Eb[i] = u;
}

// ---------------------------------------------------------------------------
// Projection GEMM body. M=16384, K=512. BM=128 x BN, BK=32; 4 waves (2x2).
// ---------------------------------------------------------------------------
template <int NC, int BN, bool TRV, bool BF16A>
__device__ __forceinline__ void proj_body(const void* __restrict__ Ein,
                                          const float* __restrict__ W,
                                          const float* __restrict__ bias,
                                          unsigned short* __restrict__ out,
                                          float scale, int bx, int by)
{
    constexpr int NB = BN / 32;
    constexpr int CPW = BN / 4;
    constexpr int KROWS = 256 / CPW;
    constexpr int BI = 32 / KROWS;

    __shared__ __align__(16) unsigned short Al[128][40];
    __shared__ __align__(16) unsigned short Bl[BN][40];

    const int tid = threadIdx.x;
    const int w = tid >> 6, l = tid & 63, g = l >> 4, li = l & 15;
    const int wm = w >> 1, wn = w & 1;
    const int row0 = bx * 128;
    const int c0 = by * BN;

    f32x4 acc[4][NB];
#pragma unroll
    for (int mb = 0; mb < 4; ++mb)
#pragma unroll
        for (int nb = 0; nb < NB; ++nb) acc[mb][nb] = (f32x4)0.0f;

    for (int kt = 0; kt < 16; ++kt) {
        const int k0 = kt * 32;
        if (BF16A) {
            const unsigned short* Eb = (const unsigned short*)Ein;
#pragma unroll
            for (int i = 0; i < 2; ++i) {
                const int r = (tid >> 2) + 64 * i;
                *(ushort8v*)&Al[r][(tid & 3) * 8] =
                    *(const ushort8v*)&Eb[(size_t)(row0 + r) * 512 + k0 + (tid & 3) * 8];
            }
        } else {
            const float* E = (const float*)Ein;
#pragma unroll
            for (int i = 0; i < 4; ++i) {
                const int r = (tid >> 3) + 32 * i;
                f32x4 v = *(const f32x4*)&E[(size_t)(row0 + r) * 512 + k0 + (tid & 7) * 4];
                ushort4v u;
#pragma unroll
                for (int j = 0; j < 4; ++j) u[j] = f2bf(v[j]);
                *(ushort4v*)&Al[r][(tid & 7) * 4] = u;
            }
        }
#pragma unroll
        for (int i = 0; i < BI; ++i) {
            const int kk = (tid / CPW) + KROWS * i;
            const int cc = (tid % CPW) * 4;
            f32x4 v = *(const f32x4*)&W[(size_t)(k0 + kk) * NC + c0 + cc];
#pragma unroll
            for (int j = 0; j < 4; ++j) Bl[cc + j][kk] = f2bf(v[j]);
        }
        __syncthreads();

        bf16x8 af[4], bw[NB];
#pragma unroll
        for (int mb = 0; mb < 4; ++mb) af[mb] = *(const bf16x8*)&Al[wm * 64 + mb * 16 + li][8 * g];
#pragma unroll
        for (int nb = 0; nb < NB; ++nb)
            bw[nb] = *(const bf16x8*)&Bl[wn * (BN / 2) + nb * 16 + li][8 * g];
#pragma unroll
        for (int mb = 0; mb < 4; ++mb)
#pragma unroll
            for (int nb = 0; nb < NB; ++nb) acc[mb][nb] = MFMA16(af[mb], bw[nb], acc[mb][nb]);
        __syncthreads();
    }

    float bv[NB];
#pragma unroll
    for (int nb = 0; nb < NB; ++nb) bv[nb] = bias[c0 + wn * (BN / 2) + nb * 16 + li];
#pragma unroll
    for (int mb = 0; mb < 4; ++mb) {
#pragma unroll
        for (int nb = 0; nb < NB; ++nb) {
            const int col = c0 + wn * (BN / 2) + nb * 16 + li;
            const int grow0 = row0 + wm * 64 + mb * 16 + 4 * g;
            if (TRV) {
                ushort4v u;
#pragma unroll
                for (int r = 0; r < 4; ++r) u[r] = f2bf((acc[mb][nb][r] + bv[nb]) * scale);
                const int bb = grow0 >> 12, n = grow0 & 4095;
                *(ushort4v*)(out + ((size_t)bb * 512 + col) * 4096 + n) = u;
            } else {
#pragma unroll
                for (int r = 0; r < 4; ++r)
                    out[(size_t)(grow0 + r) * NC + col] = f2bf((acc[mb][nb][r] + bv[nb]) * scale);
            }
        }
    }
}

template <bool BF16A>
__global__ __launch_bounds__(256) void proj_qk_kernel(const void* __restrict__ Ein,
        const float* __restrict__ wq, const float* __restrict__ bq, unsigned short* __restrict__ Qb,
        const float* __restrict__ wk, const float* __restrict__ bk, unsigned short* __restrict__ Kb)
{
    if (blockIdx.y == 0)
        proj_body<64, 64, false, BF16A>(Ein, wq, bq, Qb, 0.125f, blockIdx.x, 0);
    else
        proj_body<64, 64, false, BF16A>(Ein, wk, bk, Kb, 1.0f, blockIdx.x, 0);
}

template <bool BF16A>
__global__ __launch_bounds__(256) void proj_v_kernel(const void* __restrict__ Ein,
        const float* __restrict__ wv, const float* __restrict__ bv, unsigned short* __restrict__ Vt)
{
    proj_body<512, 128, true, BF16A>(Ein, wv, bv, Vt, 1.0f, blockIdx.x, blockIdx.y);
}

// ---------------------------------------------------------------------------
// Causal flash attention, v3 "dual-stream":
// 512 blocks = 64 qt x 4 b x 2 ch (qt-paired for balance, 2 blocks/CU).
// 8 waves; per iteration TWO 64-kv tiles: waves 0-3 do S/softmax for even tile,
// waves 4-7 for odd tile (all waves active). Online max consumes both tiles
// per step via LDS exchange. K staged in LDS (XOR-swizzled, double-buffered).
// V in regs, wave-owned 32 cols. 2 barriers per 128 kv.
// ---------------------------------------------------------------------------
__global__ __launch_bounds__(512, 4) void attn_kernel(const unsigned short* __restrict__ Qb,
                                                      const unsigned short* __restrict__ Kb,
                                                      const unsigned short* __restrict__ Vt,
                                                      float* __restrict__ out)
{
    __shared__ __align__(16) unsigned short Kl[2][2][64][64];  // [buf][tile][kv][d], chunk^row swizzle
    __shared__ __align__(16) unsigned short Pl[2][64][72];     // [grp][q][kv]
    __shared__ float pm2[2][64];
    __shared__ float rs2[64];      // group B partial row sums
    __shared__ float scl_l[64];
    __shared__ float lsum_l[64];

    const int tid = threadIdx.x;
    const int w = tid >> 6, l = tid & 63, g = l >> 4, li = l & 15;
    const int grp = w >> 2, wq4 = w & 3;
    const int bid = blockIdx.x;
    const int t = bid >> 3, b = (bid >> 1) & 3, ch = bid & 1;
    const int qt = (t < 32) ? (63 - t) : (t - 32);
    const int q0 = qt * 64;
    const int niter = (qt >> 1) + 1;
    const int rowbase = 16 * wq4 + 4 * g;  // phase-A rows rowbase..rowbase+3

    // Q fragments for rows 16*wq4 + li (both groups load the same rows)
    const unsigned short* qptr = Qb + ((size_t)(b * 4096 + q0 + 16 * wq4 + li)) * 64 + 8 * g;
    const bf16x8 QA0 = *(const bf16x8*)qptr;
    const bf16x8 QA1 = *(const bf16x8*)(qptr + 32);

    float m_r[4], l_r[4];
#pragma unroll
    for (int r = 0; r < 4; ++r) { m_r[r] = -INFINITY; l_r[r] = 0.0f; }

    f32x4 Of[4][2];
#pragma unroll
    for (int qb = 0; qb < 4; ++qb) { Of[qb][0] = (f32x4)0.0f; Of[qb][1] = (f32x4)0.0f; }

    const int cglob = ch * 256 + w * 32 + li;
    const unsigned short* vb2 = Vt + ((size_t)(b * 512 + cglob)) * 4096 + 8 * g;

    // K staging: thread stages one 16B chunk per tile. row=tid>>3, chunk=tid&7.
    const int krow = tid >> 3, kch = tid & 7;
    const unsigned short* kgb = Kb + ((size_t)(b * 4096 + krow)) * 64 + kch * 8;
    const int kslot = (kch ^ (krow & 7)) * 8;

    {   // prologue: stage pair 0 into buf 0
        ushort8v v0 = *(const ushort8v*)(kgb);
        ushort8v v1 = *(const ushort8v*)(kgb + (size_t)imin(1, qt) * 4096);
        *(ushort8v*)&Kl[0][0][krow][kslot] = v0;
        *(ushort8v*)&Kl[0][1][krow][kslot] = v1;
    }
    __syncthreads();

    for (int k = 0; k < niter; ++k) {
        const int buf = k & 1;
        const int tA = 2 * k, tB = 2 * k + 1;
        const bool actB = (tB <= qt);
        const int myt = grp ? tB : tA;
        const bool act = grp ? actB : true;

        // issue next-pair K global loads (landed into LDS later this iter)
        ushort8v kn0, kn1;
        const bool havenext = (k + 1 < niter);
        if (havenext) {
            kn0 = *(const ushort8v*)(kgb + (size_t)imin(2 * k + 2, qt) * 4096);
            kn1 = *(const ushort8v*)(kgb + (size_t)imin(2 * k + 3, qt) * 4096);
        }
        // issue this iteration's V loads (both tiles, consumed after barrier 2)
        const size_t kvA = (size_t)tA * 64;
        const size_t kvB = (size_t)imin(tB, qt) * 64;
        bf16x8 VA[2][2], VBt[2][2];
#pragma unroll
        for (int cf = 0; cf < 2; ++cf)
#pragma unroll
            for (int ks = 0; ks < 2; ++ks) {
                VA[cf][ks] = *(const bf16x8*)(vb2 + (size_t)cf * 16 * 4096 + kvA + ks * 32);
                VBt[cf][ks] = *(const bf16x8*)(vb2 + (size_t)cf * 16 * 4096 + kvB + ks * 32);
            }

        // ---- phase A: my group's tile ----
        f32x4 S[4];
        float pm[4];
        if (act) {
            const unsigned short(*Kt)[64] = Kl[buf][grp];
#pragma unroll
            for (int cb = 0; cb < 4; ++cb) {
                const int row = cb * 16 + li;
                bf16x8 K0 = *(const bf16x8*)&Kt[row][((g) ^ (row & 7)) * 8];
                bf16x8 K1 = *(const bf16x8*)&Kt[row][((4 + g) ^ (row & 7)) * 8];
                f32x4 s = (f32x4)0.0f;
                s = MFMA16(QA0, K0, s);
                s = MFMA16(QA1, K1, s);
                S[cb] = s;
            }
            if (myt == qt) {
#pragma unroll
                for (int cb = 0; cb < 4; ++cb)
#pragma unroll
                    for (int r = 0; r < 4; ++r)
                        if (cb * 16 + li > rowbase + r) S[cb][r] = -1e30f;
            }
#pragma unroll
            for (int r = 0; r < 4; ++r)
                pm[r] = fmaxf(fmaxf(S[0][r], S[1][r]), fmaxf(S[2][r], S[3][r]));
#pragma unroll
            for (int d = 1; d < 16; d <<= 1)
#pragma unroll
                for (int r = 0; r < 4; ++r) pm[r] = fmaxf(pm[r], __shfl_xor(pm[r], d));
        } else {
#pragma unroll
            for (int r = 0; r < 4; ++r) pm[r] = -INFINITY;
        }
        if (li == 0) {
#pragma unroll
            for (int r = 0; r < 4; ++r) pm2[grp][rowbase + r] = pm[r];
        }
        __syncthreads();  // barrier 1

        // joint max update (both groups compute identically for their rows)
        float sc[4];
#pragma unroll
        for (int r = 0; r < 4; ++r) {
            const float mn = fmaxf(m_r[r], fmaxf(pm2[0][rowbase + r], pm2[1][rowbase + r]));
            sc[r] = __expf(m_r[r] - mn);
            m_r[r] = mn;
        }
        if (grp == 0 && li == 0) {
#pragma unroll
            for (int r = 0; r < 4; ++r) scl_l[rowbase + r] = sc[r];
        }

        float rs[4] = {0.0f, 0.0f, 0.0f, 0.0f};
        if (act) {
#pragma unroll
            for (int cb = 0; cb < 4; ++cb)
#pragma unroll
                for (int r = 0; r < 4; ++r) {
                    const float p = __expf(S[cb][r] - m_r[r]);
                    rs[r] += p;
                    Pl[grp][rowbase + r][cb * 16 + li] = f2bf(p);
                }
#pragma unroll
            for (int d = 1; d < 16; d <<= 1)
#pragma unroll
                for (int r = 0; r < 4; ++r) rs[r] += __shfl_xor(rs[r], d);
        }
        if (grp == 1 && li == 0) {
#pragma unroll
            for (int r = 0; r < 4; ++r) rs2[rowbase + r] = rs[r];
        }

        // land next K pair into the other buffer
        if (havenext) {
            *(ushort8v*)&Kl[buf ^ 1][0][krow][kslot] = kn0;
            *(ushort8v*)&Kl[buf ^ 1][1][krow][kslot] = kn1;
        }
        __syncthreads();  // barrier 2

        if (grp == 0) {
#pragma unroll
            for (int r = 0; r < 4; ++r) l_r[r] = l_r[r] * sc[r] + rs[r] + rs2[rowbase + r];
        }

        // ---- phase B: PV, all waves, both tiles ----
#pragma unroll
        for (int qb = 0; qb < 4; ++qb) {
            f32x4 scv = *(const f32x4*)&scl_l[qb * 16 + 4 * g];
            bf16x8 PA0 = *(const bf16x8*)&Pl[0][qb * 16 + li][8 * g];
            bf16x8 PA1 = *(const bf16x8*)&Pl[0][qb * 16 + li][32 + 8 * g];
#pragma unroll
            for (int cf = 0; cf < 2; ++cf) {
                f32x4 o = Of[qb][cf];
#pragma unroll
                for (int r = 0; r < 4; ++r) o[r] *= scv[r];
                o = MFMA16(PA0, VA[cf][0], o);
                o = MFMA16(PA1, VA[cf][1], o);
                Of[qb][cf] = o;
            }
            if (actB) {
                bf16x8 PB0 = *(const bf16x8*)&Pl[1][qb * 16 + li][8 * g];
                bf16x8 PB1 = *(const bf16x8*)&Pl[1][qb * 16 + li][32 + 8 * g];
#pragma unroll
                for (int cf = 0; cf < 2; ++cf) {
                    f32x4 o = Of[qb][cf];
                    o = MFMA16(PB0, VBt[cf][0], o);
                    o = MFMA16(PB1, VBt[cf][1], o);
                    Of[qb][cf] = o;
                }
            }
        }
    }

    if (grp == 0 && li == 0) {
#pragma unroll
        for (int r = 0; r < 4; ++r) lsum_l[rowbase + r] = l_r[r];
    }
    __syncthreads();

    float* obase = out + (size_t)(b * 4096 + q0 + 4 * g) * 512 + cglob;
#pragma unroll
    for (int qb = 0; qb < 4; ++qb) {
        f32x4 lv = *(const f32x4*)&lsum_l[qb * 16 + 4 * g];
#pragma unroll
        for (int cf = 0; cf < 2; ++cf)
#pragma unroll
            for (int r = 0; r < 4; ++r)
                obase[(size_t)(qb * 16 + r) * 512 + cf * 16] = Of[qb][cf][r] / lv[r];
    }
}

// ---------------------------------------------------------------------------
extern "C" void kernel_launch(void* const* d_in, const int* in_sizes, int n_in,
                              void* d_out, int out_size, void* d_ws, size_t ws_size,
                              hipStream_t stream)
{
    (void)in_sizes; (void)n_in; (void)out_size;
    const float* E  = (const float*)d_in[0];
    const float* wq = (const float*)d_in[2];
    const float* bq = (const float*)d_in[3];
    const float* wk = (const float*)d_in[4];
    const float* bk = (const float*)d_in[5];
    const float* wv = (const float*)d_in[6];
    const float* bv = (const float*)d_in[7];

    const size_t qk_elems = (size_t)4 * 4096 * 64;
    const size_t vt_elems = (size_t)4 * 512 * 4096;
    const size_t eb_elems = (size_t)4 * 4096 * 512;

    unsigned short* Qb = (unsigned short*)d_ws;
    unsigned short* Kb = Qb + qk_elems;
    unsigned short* Vt = Kb + qk_elems;
    unsigned short* Eb = Vt + vt_elems;
    float* out = (float*)d_out;

    const size_t need_bf16 = (2 * qk_elems + vt_elems + eb_elems) * sizeof(unsigned short);
    if (ws_size >= need_bf16) {
        conv_kernel<<<dim3(4096), 256, 0, stream>>>(E, Eb);
        proj_qk_kernel<true><<<dim3(128, 2), 256, 0, stream>>>(Eb, wq, bq, Qb, wk, bk, Kb);
        proj_v_kernel<true><<<dim3(128, 4), 256, 0, stream>>>(Eb, wv, bv, Vt);
    } else {
        proj_qk_kernel<false><<<dim3(128, 2), 256, 0, stream>>>(E, wq, bq, Qb, wk, bk, Kb);
        proj_v_kernel<false><<<dim3(128, 4), 256, 0, stream>>>(E, wv, bv, Vt);
    }
    attn_kernel<<<dim3(512), 512, 0, stream>>>(Qb, Kb, Vt, out);
}